// Round 9
// baseline (137.321 us; speedup 1.0000x reference)
//
#include <hip/hip_runtime.h>
#include <hip/hip_bf16.h>

// Problem constants
#define S_LEN 2048
#define NHEAD 16
#define HDIM  64
#define DMODEL 1024

typedef unsigned short u16;
typedef __attribute__((ext_vector_type(8))) short short8;   // 8 x bf16 (4 VGPRs)
typedef __attribute__((ext_vector_type(4))) float floatx4;
typedef __attribute__((ext_vector_type(4))) u16 u16x4;

__device__ __forceinline__ u16 f2bf(float f) {
  unsigned u = __builtin_bit_cast(unsigned, f);
  u += 0x7fffu + ((u >> 16) & 1u);
  return (u16)(u >> 16);
}
__device__ __forceinline__ float bf2f(u16 b) {
  unsigned u = ((unsigned)b) << 16;
  return __builtin_bit_cast(float, u);
}
__device__ __forceinline__ void gload_lds16(const void* g, void* l) {
  __builtin_amdgcn_global_load_lds((const __attribute__((address_space(1))) unsigned int*)g,
                                   (__attribute__((address_space(3))) unsigned int*)l,
                                   16, 0, 0);
}
// XOR swizzle: spread row bits into the 16B-slot bits (involution, 16B granularity).
// Verified R2-R8: SQ_LDS_BANK_CONFLICT == 0 on staged K/V & GEMM tiles; read-side masks
// are lane-constant (row bits 7-9 depend only on lane) -> hoisted bases, immediate offsets.
__device__ __forceinline__ int swz(int b) { return b ^ (((b >> 7) & 7) << 4); }

#define MFMA16(a, b, c) __builtin_amdgcn_mfma_f32_16x16x32_bf16(a, b, c, 0, 0, 0)

// ---------------- conversion kernels ----------------

__global__ __launch_bounds__(256) void k_cast(const float* __restrict__ in,
                                              u16* __restrict__ hi, int n) {
  int i = (blockIdx.x * blockDim.x + threadIdx.x) * 4;
  if (i >= n) return;
  float4 v = *(const float4*)(in + i);
  u16x4 hv = {f2bf(v.x), f2bf(v.y), f2bf(v.z), f2bf(v.w)};
  *(u16x4*)(hi + i) = hv;
}

// in: [R][C] f32  ->  oh: [C][R] bf16 (transposed)
__global__ void k_transpose(const float* __restrict__ in, u16* __restrict__ oh, int R, int C) {
  __shared__ float t[32][33];
  int c0 = blockIdx.x * 32, r0 = blockIdx.y * 32;
  int tx = threadIdx.x, ty = threadIdx.y;
#pragma unroll
  for (int rr = ty; rr < 32; rr += 8) t[rr][tx] = in[(size_t)(r0 + rr) * C + c0 + tx];
  __syncthreads();
#pragma unroll
  for (int rr = ty; rr < 32; rr += 8) {
    float v = t[tx][rr];
    oh[(size_t)(c0 + rr) * R + r0 + tx] = f2bf(v);
  }
}

// ---------------- bf16 GEMM mainloop (m97 2-buffer structure — R3-proven 669+ TF) ----------------
// C[128x128] = A[128x1024] * B^T, B stored [N][K=1024].
// R8 post-mortem: 3-buffer counted-vmcnt variant measured 549 TF (20% slower) -> reverted.
__device__ __forceinline__ void gemm_main(const u16* __restrict__ A, const u16* __restrict__ B,
                                          int m0, int n0, floatx4 (&acc)[4][4]) {
  __shared__ __align__(16) u16 sA[2][128 * 32];
  __shared__ __align__(16) u16 sB[2][128 * 32];
  const int tid = threadIdx.x, lane = tid & 63;
  const int wid = tid >> 6, wr = wid >> 1, wc = wid & 1;
  const int cl = lane & 15, hi = lane >> 4;
  // hoisted swizzled read bases: b = w*4096 + i*1024 + cl*64 + hi*16, (b>>7)&7 == (cl>>1)&7
  const int rmask = ((cl >> 1) & 7) << 4;
  const int aoff = (wr * 4096 + cl * 64 + hi * 16) ^ rmask;
  const int boff = (wc * 4096 + cl * 64 + hi * 16) ^ rmask;
#pragma unroll
  for (int i = 0; i < 4; ++i)
#pragma unroll
    for (int j = 0; j < 4; ++j) acc[i][j] = (floatx4){0.f, 0.f, 0.f, 0.f};

  auto stage = [&](int buf, int kt) {   // 4 loads/thread
    int k0 = kt * 32;
#pragma unroll
    for (int it = 0; it < 2; ++it) {
      // linear LDS dest; source address pre-swizzled so swizzled reads see consistent data
      int p = (it * 256 + tid) * 16;
      int q = swz(p);
      int row = q >> 6, colb = q & 63;
      int base = (it * 256 + (tid & ~63)) * 16;   // wave-uniform LDS base (HW adds lane*16)
      gload_lds16((const char*)A + (size_t)(m0 + row) * 2048 + k0 * 2 + colb, (char*)sA[buf] + base);
      gload_lds16((const char*)B + (size_t)(n0 + row) * 2048 + k0 * 2 + colb, (char*)sB[buf] + base);
    }
  };
  stage(0, 0);
  __syncthreads();
  for (int kt = 0; kt < 32; ++kt) {
    int cur = kt & 1;
    if (kt + 1 < 32) stage(cur ^ 1, kt + 1);
    short8 a[4], b[4];
#pragma unroll
    for (int i = 0; i < 4; ++i) {
      a[i] = *(const short8*)((const char*)sA[cur] + aoff + i * 1024);
      b[i] = *(const short8*)((const char*)sB[cur] + boff + i * 1024);
    }
    __builtin_amdgcn_s_setprio(1);
#pragma unroll
    for (int i = 0; i < 4; ++i)
#pragma unroll
      for (int j = 0; j < 4; ++j)
        acc[i][j] = MFMA16(a[i], b[j], acc[i][j]);
    __builtin_amdgcn_s_setprio(0);
    __syncthreads();
  }
}

// ---------------- QKV projection ----------------
// Writes Q,K as [B*H][S][64] bf16, V transposed as [B*H][64][S] bf16.
__global__ __launch_bounds__(256) void k_qkv_gemm(const u16* __restrict__ xh,
                                                  const u16* __restrict__ wh,
                                                  const float* __restrict__ bqkv,
                                                  u16* __restrict__ Qb, u16* __restrict__ Kb,
                                                  u16* __restrict__ Vt) {
  // XCD swizzle (T1): 768 blocks, 96/XCD -> each XCD owns 4 contiguous m-tiles x all n
  // (verified R8: FETCH 71.8 -> 28.8 MB)
  int bid = blockIdx.y * 24 + blockIdx.x;
  int sid = (bid & 7) * 96 + (bid >> 3);
  int m0 = (sid / 24) * 128, n0 = (sid % 24) * 128;
  floatx4 acc[4][4];
  gemm_main(xh, wh, m0, n0, acc);
  const int lane = threadIdx.x & 63, wid = threadIdx.x >> 6;
  const int wr = wid >> 1, wc = wid & 1;
#pragma unroll
  for (int j = 0; j < 4; ++j) {
    int n = n0 + wc * 64 + j * 16 + (lane & 15);
    float bias = bqkv[n];
    int h = n / 192;
    int rr = n - h * 192;
#pragma unroll
    for (int i = 0; i < 4; ++i) {
#pragma unroll
      for (int r = 0; r < 4; ++r) {
        int m = m0 + wr * 64 + i * 16 + (lane >> 4) * 4 + r;
        int b = m >> 11, s = m & 2047;
        float v = acc[i][j][r] + bias;
        u16 bv = f2bf(v);
        int bh = b * 16 + h;
        if (rr < 64)
          Qb[((size_t)bh * 2048 + s) * 64 + rr] = bv;
        else if (rr < 128)
          Kb[((size_t)bh * 2048 + s) * 64 + (rr - 64)] = bv;
        else
          Vt[((size_t)bh * 64 + (rr - 128)) * 2048 + s] = bv;
      }
    }
  }
}

// ---------------- causal flash attention, KV-split ----------------
// Fixed-max softmax (p = exp(s/8 - 16), no rescale) makes attention LINEAR over key
// chunks: partial (O, l) from disjoint key ranges just add. Each block = (bh, qt, chunk
// of <=8 kv-tiles). qt<4 (single chunk): write ao directly. Else: write unnormalized
// bf16 partial O + f32 partial l; k_attn_reduce sums and normalizes.
// 8 waves x 16 q-rows, swapped QK^T, hoisted swizzle bases.
__global__ __launch_bounds__(512, 6) void k_attn(const u16* __restrict__ Qb,
                                                 const u16* __restrict__ Kb,
                                                 const u16* __restrict__ Vt,
                                                 u16* __restrict__ ao,
                                                 u16* __restrict__ pO,
                                                 float* __restrict__ pL) {
  // bid ordering: all 40 chunks of a bh land on XCD bh%8 (round-robin dispatch)
  const int bid = blockIdx.x;
  const int bh = (bid & 7) + 8 * ((bid >> 3) / 40);
  const int idx = (bid >> 3) % 40;
  int qt, c;
  if (idx < 4)        { qt = idx;                   c = 0; }
  else if (idx < 12)  { qt = 4 + ((idx - 4) >> 1);  c = (idx - 4) & 1; }
  else if (idx < 24)  { qt = 8 + (idx - 12) / 3;    c = (idx - 12) % 3; }
  else                { qt = 12 + ((idx - 24) >> 2); c = (idx - 24) & 3; }
  const int q0 = qt * 128;
  const int tid = threadIdx.x, lane = tid & 63, wid = tid >> 6;   // wid 0..7
  const int cl = lane & 15, hi = lane >> 4;
  const int wq0 = q0 + wid * 16;
  const int myq = wq0 + cl;
  const u16* Qp = Qb + (size_t)bh * (S_LEN * HDIM);
  const u16* Kp = Kb + (size_t)bh * (S_LEN * HDIM);
  const u16* Vp = Vt + (size_t)bh * (HDIM * S_LEN);

  __shared__ __align__(16) u16 Kl[2][64 * 64];
  __shared__ __align__(16) u16 Vl[2][64 * 64];
  __shared__ __align__(16) u16 Pl[8][16 * 72];   // per-wave 16 q-rows x 64 keys, 144B stride

  // hoisted swizzled K/V read bases: b = fc*2048 + cl*128 + kf*64 + hi*16, (b>>7)&7 == cl&7
  const int kvo0 = (cl * 128 + hi * 16) ^ ((cl & 7) << 4);
  const int kvo1 = kvo0 ^ 64;

  short8 qf[2];
#pragma unroll
  for (int kf = 0; kf < 2; ++kf)
    qf[kf] = *(const short8*)&Qp[(size_t)myq * 64 + kf * 32 + hi * 8];

  floatx4 o[4];
#pragma unroll
  for (int fc = 0; fc < 4; ++fc) o[fc] = (floatx4){0.f, 0.f, 0.f, 0.f};
  float lrun = 0.f;

  const int t0 = c * 8;
  const int NTb = min(t0 + 8, 2 * qt + 2);   // block tiles in this chunk
  const int NTw = 2 * qt + 1 + (wid >> 2);   // wave causal bound; t==NTw-1 is diagonal
  const float C1 = 0.125f * 1.44269504f;     // scale * log2(e)
  const float C2 = 16.0f * 1.44269504f;      // fixed max * log2(e)

  auto stage = [&](int buf, int kv0) {       // 2 loads/thread (512 threads)
    int p = tid * 16;
    int q = swz(p);
    int row = q >> 7, colb = q & 127;
    int base = (tid & ~63) * 16;
    gload_lds16((const char*)Kp + (size_t)(kv0 + row) * 128 + colb, (char*)Kl[buf] + base);
    gload_lds16((const char*)Vp + (size_t)row * 4096 + (size_t)kv0 * 2 + colb, (char*)Vl[buf] + base);
  };
  stage(0, t0 * 64);

  for (int t = t0; t < NTb; ++t) {
    int cur = t & 1;
    asm volatile("s_waitcnt vmcnt(0)" ::: "memory");
    __builtin_amdgcn_s_barrier();      // stage(t) landed; buf[t-1] readers done
    if (t + 1 < NTb) stage(cur ^ 1, (t + 1) * 64);
    if (t < NTw) {
      int kv0 = t * 64;
      // ---- QK^T (swapped: A=K, B=Q -> lane: query cl, keys fc*16+hi*4+j) ----
      floatx4 sc[4];
#pragma unroll
      for (int fc = 0; fc < 4; ++fc) sc[fc] = (floatx4){0.f, 0.f, 0.f, 0.f};
      __builtin_amdgcn_s_setprio(1);
#pragma unroll
      for (int kf = 0; kf < 2; ++kf) {
        const char* kb = (const char*)Kl[cur] + (kf ? kvo1 : kvo0);
        short8 kfv[4];
#pragma unroll
        for (int fc = 0; fc < 4; ++fc)
          kfv[fc] = *(const short8*)(kb + fc * 2048);
#pragma unroll
        for (int fc = 0; fc < 4; ++fc)
          sc[fc] = MFMA16(kfv[fc], qf[kf], sc[fc]);
      }
      __builtin_amdgcn_s_setprio(0);
      // ---- fixed-max softmax; mask only on the wave's diagonal (last) tile ----
      auto smax = [&](bool masked) {
        float ls = 0.f;
#pragma unroll
        for (int fc = 0; fc < 4; ++fc) {
          float p0 = exp2f(sc[fc][0] * C1 - C2);
          float p1 = exp2f(sc[fc][1] * C1 - C2);
          float p2 = exp2f(sc[fc][2] * C1 - C2);
          float p3 = exp2f(sc[fc][3] * C1 - C2);
          if (masked) {
            int key = kv0 + fc * 16 + hi * 4;
            p0 = (key + 0 <= myq) ? p0 : 0.f;
            p1 = (key + 1 <= myq) ? p1 : 0.f;
            p2 = (key + 2 <= myq) ? p2 : 0.f;
            p3 = (key + 3 <= myq) ? p3 : 0.f;
          }
          unsigned r0, r1;
          asm("v_cvt_pk_bf16_f32 %0, %1, %2" : "=v"(r0) : "v"(p0), "v"(p1));
          asm("v_cvt_pk_bf16_f32 %0, %1, %2" : "=v"(r1) : "v"(p2), "v"(p3));
          uint2 rr; rr.x = r0; rr.y = r1;
          *(uint2*)((char*)Pl[wid] + cl * 144 + fc * 32 + hi * 8) = rr;
          ls += (p0 + p1) + (p2 + p3);
        }
        lrun += ls;
      };
      if (t == NTw - 1) smax(true); else smax(false);
      // ---- PV: A = P[q][key] (contiguous), B = V^T[d][key] ----
      __builtin_amdgcn_s_setprio(1);
#pragma unroll
      for (int kf = 0; kf < 2; ++kf) {
        short8 pa = *(const short8*)((const char*)Pl[wid] + cl * 144 + kf * 64 + hi * 16);
        const char* vbp = (const char*)Vl[cur] + (kf ? kvo1 : kvo0);
        short8 vb[4];
#pragma unroll
        for (int fc = 0; fc < 4; ++fc)
          vb[fc] = *(const short8*)(vbp + fc * 2048);
#pragma unroll
        for (int fc = 0; fc < 4; ++fc)
          o[fc] = MFMA16(pa, vb[fc], o[fc]);
      }
      __builtin_amdgcn_s_setprio(0);
    }
  }
  // ---- epilogue ----
  float l = lrun;
  l += __shfl_xor(l, 16);
  l += __shfl_xor(l, 32);   // lanes {cl,+16,+32,+48} hold full chunk-sum for query wq0+cl
  if (qt < 4) {
    // single chunk: normalize and write ao directly
    const int b = bh >> 4, h = bh & 15;
#pragma unroll
    for (int j = 0; j < 4; ++j) {
      float inv = 1.f / __shfl(l, hi * 4 + j);   // full sum for row hi*4+j
      int q = wq0 + hi * 4 + j;
#pragma unroll
      for (int fc = 0; fc < 4; ++fc) {
        size_t idx2 = ((size_t)b * 2048 + q) * 1024 + h * 64 + fc * 16 + cl;
        ao[idx2] = f2bf(o[fc][j] * inv);
      }
    }
  } else {
    // partial: unnormalized bf16 O + f32 l  (slot indexed by qt-4)
    const int slot = (bh * 12 + (qt - 4)) * 4 + c;
    u16* po = pO + (size_t)slot * 8192 + (size_t)wid * 16 * 64;
    if (hi == 0) pL[slot * 128 + wid * 16 + cl] = l;
#pragma unroll
    for (int j = 0; j < 4; ++j) {
      int row = hi * 4 + j;
#pragma unroll
      for (int fc = 0; fc < 4; ++fc)
        po[row * 64 + fc * 16 + cl] = f2bf(o[fc][j]);
    }
  }
}

// ---------------- attention partial reduce ----------------
// For qt>=4: ao[row] = (sum_c O_c[row]) / (sum_c l_c[row])
__global__ __launch_bounds__(256) void k_attn_reduce(const u16* __restrict__ pO,
                                                     const float* __restrict__ pL,
                                                     u16* __restrict__ ao) {
  int e = blockIdx.x * 256 + threadIdx.x;   // 32 bh x 12 qt x 128 row x 64 d
  int d = e & 63;
  int row = (e >> 6) & 127;
  int t = e >> 13;                          // bh*12 + (qt-4)
  int qt = 4 + t % 12;
  int bh = t / 12;
  int nch = (2 * qt + 9) >> 3;              // ceil((2qt+2)/8) in 2..4
  int slot = t * 4;
  size_t obase = (size_t)slot * 8192 + row * 64 + d;
  float O = 0.f, l = 0.f;
  for (int c = 0; c < nch; ++c) {
    O += bf2f(pO[obase + (size_t)c * 8192]);
    l += pL[(slot + c) * 128 + row];
  }
  int b = bh >> 4, h = bh & 15;
  int q = qt * 128 + row;
  ao[((size_t)b * 2048 + q) * 1024 + h * 64 + d] = f2bf(O / l);
}

// ---------------- output projection ----------------
__global__ __launch_bounds__(256) void k_out_gemm(const u16* __restrict__ ao,
                                                  const u16* __restrict__ woh,
                                                  const float* __restrict__ bo, float* __restrict__ out) {
  // XCD swizzle (T1): 256 blocks, 32/XCD -> each XCD owns 4 contiguous m-tiles x all n
  int bid = blockIdx.y * 8 + blockIdx.x;
  int sid = (bid & 7) * 32 + (bid >> 3);
  int m0 = (sid >> 3) * 128, n0 = (sid & 7) * 128;
  floatx4 acc[4][4];
  gemm_main(ao, woh, m0, n0, acc);
  const int lane = threadIdx.x & 63, wid = threadIdx.x >> 6;
  const int wr = wid >> 1, wc = wid & 1;
#pragma unroll
  for (int j = 0; j < 4; ++j) {
    int n = n0 + wc * 64 + j * 16 + (lane & 15);
    float bias = bo[n];
#pragma unroll
    for (int i = 0; i < 4; ++i) {
#pragma unroll
      for (int r = 0; r < 4; ++r) {
        int m = m0 + wr * 64 + i * 16 + (lane >> 4) * 4 + r;
        out[(size_t)m * 1024 + n] = acc[i][j][r] + bias;
      }
    }
  }
}

// ---------------- launch ----------------
extern "C" void kernel_launch(void* const* d_in, const int* in_sizes, int n_in,
                              void* d_out, int out_size, void* d_ws, size_t ws_size,
                              hipStream_t stream) {
  (void)in_sizes; (void)n_in; (void)out_size; (void)ws_size;
  const float* x    = (const float*)d_in[0];
  // d_in[1] = causal mask (tril) — implied by kernel structure, not read
  const float* Wqkv = (const float*)d_in[2];
  const float* bqkv = (const float*)d_in[3];
  const float* Wo   = (const float*)d_in[4];
  const float* bo   = (const float*)d_in[5];
  float* out = (float*)d_out;

  u16* p = (u16*)d_ws;
  u16* xh  = p; p += 4194304;   // [4096][1024] — reused as ao after QKV GEMM
  u16* wh  = p; p += 3145728;   // WqkvT [3072][1024] bf16
  u16* woh = p; p += 1048576;   // WoT   [1024][1024] bf16
  u16* Qb  = p; p += 4194304;   // [B*H][S][64]
  u16* Kb  = p; p += 4194304;
  u16* Vt  = p; p += 4194304;   // [B*H][64][S]
  u16* pO  = p; p += 12582912;  // partial O: [32*12*4 slots][128][64] bf16 (qt>=4)
  float* pL = (float*)p; p += 393216;  // partial l: [32*12*4][128] f32
  u16* ao  = xh;                // alias: x dead after QKV GEMM

  k_cast<<<4096, 256, 0, stream>>>(x, xh, 4194304);
  k_transpose<<<dim3(96, 32), dim3(32, 8), 0, stream>>>(Wqkv, wh, 1024, 3072);
  k_transpose<<<dim3(32, 32), dim3(32, 8), 0, stream>>>(Wo, woh, 1024, 1024);
  k_qkv_gemm<<<dim3(24, 32), 256, 0, stream>>>(xh, wh, bqkv, Qb, Kb, Vt);
  k_attn<<<1280, 512, 0, stream>>>(Qb, Kb, Vt, ao, pO, pL);
  k_attn_reduce<<<12288, 256, 0, stream>>>(pO, pL, ao);
  k_out_gemm<<<dim3(8, 32), 256, 0, stream>>>(ao, woh, bo, out);
}

// Round 10
// 128.844 us; speedup vs baseline: 1.0658x; 1.0658x over previous
//
#include <hip/hip_runtime.h>
#include <hip/hip_bf16.h>

// Problem constants
#define S_LEN 2048
#define NHEAD 16
#define HDIM  64
#define DMODEL 1024

typedef unsigned short u16;
typedef __attribute__((ext_vector_type(8))) short short8;   // 8 x bf16 (4 VGPRs)
typedef __attribute__((ext_vector_type(4))) float floatx4;
typedef __attribute__((ext_vector_type(4))) u16 u16x4;

__device__ __forceinline__ u16 f2bf(float f) {
  unsigned u = __builtin_bit_cast(unsigned, f);
  u += 0x7fffu + ((u >> 16) & 1u);
  return (u16)(u >> 16);
}
__device__ __forceinline__ float bf2f(u16 b) {
  unsigned u = ((unsigned)b) << 16;
  return __builtin_bit_cast(float, u);
}
__device__ __forceinline__ void gload_lds16(const void* g, void* l) {
  __builtin_amdgcn_global_load_lds((const __attribute__((address_space(1))) unsigned int*)g,
                                   (__attribute__((address_space(3))) unsigned int*)l,
                                   16, 0, 0);
}
// XOR swizzle: spread row bits into the 16B-slot bits (involution, 16B granularity).
// Verified R2-R9: SQ_LDS_BANK_CONFLICT == 0 on staged K/V & GEMM tiles; read-side masks
// are lane-constant (row bits 7-9 depend only on lane) -> hoisted bases, immediate offsets.
__device__ __forceinline__ int swz(int b) { return b ^ (((b >> 7) & 7) << 4); }

#define MFMA16(a, b, c) __builtin_amdgcn_mfma_f32_16x16x32_bf16(a, b, c, 0, 0, 0)

// ---------------- conversion kernels ----------------

__global__ __launch_bounds__(256) void k_cast(const float* __restrict__ in,
                                              u16* __restrict__ hi, int n) {
  int i = (blockIdx.x * blockDim.x + threadIdx.x) * 4;
  if (i >= n) return;
  float4 v = *(const float4*)(in + i);
  u16x4 hv = {f2bf(v.x), f2bf(v.y), f2bf(v.z), f2bf(v.w)};
  *(u16x4*)(hi + i) = hv;
}

// in: [R][C] f32  ->  oh: [C][R] bf16 (transposed)
__global__ void k_transpose(const float* __restrict__ in, u16* __restrict__ oh, int R, int C) {
  __shared__ float t[32][33];
  int c0 = blockIdx.x * 32, r0 = blockIdx.y * 32;
  int tx = threadIdx.x, ty = threadIdx.y;
#pragma unroll
  for (int rr = ty; rr < 32; rr += 8) t[rr][tx] = in[(size_t)(r0 + rr) * C + c0 + tx];
  __syncthreads();
#pragma unroll
  for (int rr = ty; rr < 32; rr += 8) {
    float v = t[tx][rr];
    oh[(size_t)(c0 + rr) * R + r0 + tx] = f2bf(v);
  }
}

// ---------------- bf16 GEMM mainloop (m97 2-buffer structure) ----------------
// C[128x128] = A[128x1024] * B^T, B stored [N][K=1024].
__device__ __forceinline__ void gemm_main(const u16* __restrict__ A, const u16* __restrict__ B,
                                          int m0, int n0, floatx4 (&acc)[4][4]) {
  __shared__ __align__(16) u16 sA[2][128 * 32];
  __shared__ __align__(16) u16 sB[2][128 * 32];
  const int tid = threadIdx.x, lane = tid & 63;
  const int wid = tid >> 6, wr = wid >> 1, wc = wid & 1;
  const int cl = lane & 15, hi = lane >> 4;
  // hoisted swizzled read bases: b = w*4096 + i*1024 + cl*64 + hi*16, (b>>7)&7 == (cl>>1)&7
  const int rmask = ((cl >> 1) & 7) << 4;
  const int aoff = (wr * 4096 + cl * 64 + hi * 16) ^ rmask;
  const int boff = (wc * 4096 + cl * 64 + hi * 16) ^ rmask;
#pragma unroll
  for (int i = 0; i < 4; ++i)
#pragma unroll
    for (int j = 0; j < 4; ++j) acc[i][j] = (floatx4){0.f, 0.f, 0.f, 0.f};

  auto stage = [&](int buf, int kt) {   // 4 loads/thread
    int k0 = kt * 32;
#pragma unroll
    for (int it = 0; it < 2; ++it) {
      // linear LDS dest; source address pre-swizzled so swizzled reads see consistent data
      int p = (it * 256 + tid) * 16;
      int q = swz(p);
      int row = q >> 6, colb = q & 63;
      int base = (it * 256 + (tid & ~63)) * 16;   // wave-uniform LDS base (HW adds lane*16)
      gload_lds16((const char*)A + (size_t)(m0 + row) * 2048 + k0 * 2 + colb, (char*)sA[buf] + base);
      gload_lds16((const char*)B + (size_t)(n0 + row) * 2048 + k0 * 2 + colb, (char*)sB[buf] + base);
    }
  };
  stage(0, 0);
  __syncthreads();
  for (int kt = 0; kt < 32; ++kt) {
    int cur = kt & 1;
    if (kt + 1 < 32) stage(cur ^ 1, kt + 1);
    short8 a[4], b[4];
#pragma unroll
    for (int i = 0; i < 4; ++i) {
      a[i] = *(const short8*)((const char*)sA[cur] + aoff + i * 1024);
      b[i] = *(const short8*)((const char*)sB[cur] + boff + i * 1024);
    }
    __builtin_amdgcn_s_setprio(1);
#pragma unroll
    for (int i = 0; i < 4; ++i)
#pragma unroll
      for (int j = 0; j < 4; ++j)
        acc[i][j] = MFMA16(a[i], b[j], acc[i][j]);
    __builtin_amdgcn_s_setprio(0);
    __syncthreads();
  }
}

// ---------------- bf16 GEMM mainloop, 128x64 tile (for N=1024 out-proj: 512 blocks = 2/CU) ----------------
// R9 post-mortem: 128x128 out_gemm grid = 256 blocks = 1 block/CU -> no co-resident block to
// overlap the per-step barrier drain (est ~30us hidden). 128x64 doubles concurrency, 24KB LDS.
__device__ __forceinline__ void gemm_main_n64(const u16* __restrict__ A, const u16* __restrict__ B,
                                              int m0, int n0, floatx4 (&acc)[4][2]) {
  __shared__ __align__(16) u16 sA[2][128 * 32];
  __shared__ __align__(16) u16 sB[2][64 * 32];
  const int tid = threadIdx.x, lane = tid & 63;
  const int wid = tid >> 6, wr = wid >> 1, wc = wid & 1;
  const int cl = lane & 15, hi = lane >> 4;
  const int rmask = ((cl >> 1) & 7) << 4;
  const int aoff = (wr * 4096 + cl * 64 + hi * 16) ^ rmask;
  const int boff = (wc * 2048 + cl * 64 + hi * 16) ^ rmask;   // wave n-half = wc*32 rows
#pragma unroll
  for (int i = 0; i < 4; ++i)
#pragma unroll
    for (int j = 0; j < 2; ++j) acc[i][j] = (floatx4){0.f, 0.f, 0.f, 0.f};

  auto stage = [&](int buf, int kt) {   // 3 loads/thread (A: 2, B: 1)
    int k0 = kt * 32;
#pragma unroll
    for (int it = 0; it < 2; ++it) {
      int p = (it * 256 + tid) * 16;
      int q = swz(p);
      int row = q >> 6, colb = q & 63;
      int base = (it * 256 + (tid & ~63)) * 16;
      gload_lds16((const char*)A + (size_t)(m0 + row) * 2048 + k0 * 2 + colb, (char*)sA[buf] + base);
    }
    {
      int p = tid * 16;                 // 4KB B tile, one pass
      int q = swz(p);
      int row = q >> 6, colb = q & 63;
      int base = (tid & ~63) * 16;
      gload_lds16((const char*)B + (size_t)(n0 + row) * 2048 + k0 * 2 + colb, (char*)sB[buf] + base);
    }
  };
  stage(0, 0);
  __syncthreads();
  for (int kt = 0; kt < 32; ++kt) {
    int cur = kt & 1;
    if (kt + 1 < 32) stage(cur ^ 1, kt + 1);
    short8 a[4], b[2];
#pragma unroll
    for (int i = 0; i < 4; ++i)
      a[i] = *(const short8*)((const char*)sA[cur] + aoff + i * 1024);
#pragma unroll
    for (int j = 0; j < 2; ++j)
      b[j] = *(const short8*)((const char*)sB[cur] + boff + j * 1024);
    __builtin_amdgcn_s_setprio(1);
#pragma unroll
    for (int i = 0; i < 4; ++i)
#pragma unroll
      for (int j = 0; j < 2; ++j)
        acc[i][j] = MFMA16(a[i], b[j], acc[i][j]);
    __builtin_amdgcn_s_setprio(0);
    __syncthreads();
  }
}

// ---------------- QKV projection ----------------
// Writes Q,K as [B*H][S][64] bf16, V transposed as [B*H][64][S] bf16.
__global__ __launch_bounds__(256) void k_qkv_gemm(const u16* __restrict__ xh,
                                                  const u16* __restrict__ wh,
                                                  const float* __restrict__ bqkv,
                                                  u16* __restrict__ Qb, u16* __restrict__ Kb,
                                                  u16* __restrict__ Vt) {
  // XCD swizzle (T1): 768 blocks, 96/XCD (verified R8: FETCH 71.8 -> 28.8 MB)
  int bid = blockIdx.y * 24 + blockIdx.x;
  int sid = (bid & 7) * 96 + (bid >> 3);
  int m0 = (sid / 24) * 128, n0 = (sid % 24) * 128;
  floatx4 acc[4][4];
  gemm_main(xh, wh, m0, n0, acc);
  const int lane = threadIdx.x & 63, wid = threadIdx.x >> 6;
  const int wr = wid >> 1, wc = wid & 1;
#pragma unroll
  for (int j = 0; j < 4; ++j) {
    int n = n0 + wc * 64 + j * 16 + (lane & 15);
    float bias = bqkv[n];
    int h = n / 192;
    int rr = n - h * 192;
#pragma unroll
    for (int i = 0; i < 4; ++i) {
#pragma unroll
      for (int r = 0; r < 4; ++r) {
        int m = m0 + wr * 64 + i * 16 + (lane >> 4) * 4 + r;
        int b = m >> 11, s = m & 2047;
        float v = acc[i][j][r] + bias;
        u16 bv = f2bf(v);
        int bh = b * 16 + h;
        if (rr < 64)
          Qb[((size_t)bh * 2048 + s) * 64 + rr] = bv;
        else if (rr < 128)
          Kb[((size_t)bh * 2048 + s) * 64 + (rr - 64)] = bv;
        else
          Vt[((size_t)bh * 64 + (rr - 128)) * 2048 + s] = bv;
      }
    }
  }
}

// ---------------- causal flash attention, KV-split ----------------
// Fixed-max softmax (p = exp(s/8 - 16), no rescale) makes attention LINEAR over key
// chunks: partial (O, l) from disjoint key ranges just add. Each block = (bh, qt, chunk
// of <=8 kv-tiles). qt<4 (single chunk): write ao directly. Else: write unnormalized
// bf16 partial O + f32 partial l; k_attn_reduce sums and normalizes.
// 8 waves x 16 q-rows, swapped QK^T, hoisted swizzle bases.
__global__ __launch_bounds__(512, 6) void k_attn(const u16* __restrict__ Qb,
                                                 const u16* __restrict__ Kb,
                                                 const u16* __restrict__ Vt,
                                                 u16* __restrict__ ao,
                                                 u16* __restrict__ pO,
                                                 float* __restrict__ pL) {
  // bid ordering: all 40 chunks of a bh land on XCD bh%8 (round-robin dispatch)
  const int bid = blockIdx.x;
  const int bh = (bid & 7) + 8 * ((bid >> 3) / 40);
  const int idx = (bid >> 3) % 40;
  int qt, c;
  if (idx < 4)        { qt = idx;                   c = 0; }
  else if (idx < 12)  { qt = 4 + ((idx - 4) >> 1);  c = (idx - 4) & 1; }
  else if (idx < 24)  { qt = 8 + (idx - 12) / 3;    c = (idx - 12) % 3; }
  else                { qt = 12 + ((idx - 24) >> 2); c = (idx - 24) & 3; }
  const int q0 = qt * 128;
  const int tid = threadIdx.x, lane = tid & 63, wid = tid >> 6;   // wid 0..7
  const int cl = lane & 15, hi = lane >> 4;
  const int wq0 = q0 + wid * 16;
  const int myq = wq0 + cl;
  const u16* Qp = Qb + (size_t)bh * (S_LEN * HDIM);
  const u16* Kp = Kb + (size_t)bh * (S_LEN * HDIM);
  const u16* Vp = Vt + (size_t)bh * (HDIM * S_LEN);

  __shared__ __align__(16) u16 Kl[2][64 * 64];
  __shared__ __align__(16) u16 Vl[2][64 * 64];
  __shared__ __align__(16) u16 Pl[8][16 * 72];   // per-wave 16 q-rows x 64 keys, 144B stride

  // hoisted swizzled K/V read bases: b = fc*2048 + cl*128 + kf*64 + hi*16, (b>>7)&7 == cl&7
  const int kvo0 = (cl * 128 + hi * 16) ^ ((cl & 7) << 4);
  const int kvo1 = kvo0 ^ 64;

  short8 qf[2];
#pragma unroll
  for (int kf = 0; kf < 2; ++kf)
    qf[kf] = *(const short8*)&Qp[(size_t)myq * 64 + kf * 32 + hi * 8];

  floatx4 o[4];
#pragma unroll
  for (int fc = 0; fc < 4; ++fc) o[fc] = (floatx4){0.f, 0.f, 0.f, 0.f};
  float lrun = 0.f;

  const int t0 = c * 8;
  const int NTb = min(t0 + 8, 2 * qt + 2);   // block tiles in this chunk
  const int NTw = 2 * qt + 1 + (wid >> 2);   // wave causal bound; t==NTw-1 is diagonal
  const float C1 = 0.125f * 1.44269504f;     // scale * log2(e)
  const float C2 = 16.0f * 1.44269504f;      // fixed max * log2(e)

  auto stage = [&](int buf, int kv0) {       // 2 loads/thread (512 threads)
    int p = tid * 16;
    int q = swz(p);
    int row = q >> 7, colb = q & 127;
    int base = (tid & ~63) * 16;
    gload_lds16((const char*)Kp + (size_t)(kv0 + row) * 128 + colb, (char*)Kl[buf] + base);
    gload_lds16((const char*)Vp + (size_t)row * 4096 + (size_t)kv0 * 2 + colb, (char*)Vl[buf] + base);
  };
  stage(0, t0 * 64);

  for (int t = t0; t < NTb; ++t) {
    int cur = t & 1;
    asm volatile("s_waitcnt vmcnt(0)" ::: "memory");
    __builtin_amdgcn_s_barrier();      // stage(t) landed; buf[t-1] readers done
    if (t + 1 < NTb) stage(cur ^ 1, (t + 1) * 64);
    if (t < NTw) {
      int kv0 = t * 64;
      // ---- QK^T (swapped: A=K, B=Q -> lane: query cl, keys fc*16+hi*4+j) ----
      floatx4 sc[4];
#pragma unroll
      for (int fc = 0; fc < 4; ++fc) sc[fc] = (floatx4){0.f, 0.f, 0.f, 0.f};
      __builtin_amdgcn_s_setprio(1);
#pragma unroll
      for (int kf = 0; kf < 2; ++kf) {
        const char* kb = (const char*)Kl[cur] + (kf ? kvo1 : kvo0);
        short8 kfv[4];
#pragma unroll
        for (int fc = 0; fc < 4; ++fc)
          kfv[fc] = *(const short8*)(kb + fc * 2048);
#pragma unroll
        for (int fc = 0; fc < 4; ++fc)
          sc[fc] = MFMA16(kfv[fc], qf[kf], sc[fc]);
      }
      __builtin_amdgcn_s_setprio(0);
      // ---- fixed-max softmax; mask only on the wave's diagonal (last) tile ----
      auto smax = [&](bool masked) {
        float ls = 0.f;
#pragma unroll
        for (int fc = 0; fc < 4; ++fc) {
          float p0 = exp2f(sc[fc][0] * C1 - C2);
          float p1 = exp2f(sc[fc][1] * C1 - C2);
          float p2 = exp2f(sc[fc][2] * C1 - C2);
          float p3 = exp2f(sc[fc][3] * C1 - C2);
          if (masked) {
            int key = kv0 + fc * 16 + hi * 4;
            p0 = (key + 0 <= myq) ? p0 : 0.f;
            p1 = (key + 1 <= myq) ? p1 : 0.f;
            p2 = (key + 2 <= myq) ? p2 : 0.f;
            p3 = (key + 3 <= myq) ? p3 : 0.f;
          }
          unsigned r0, r1;
          asm("v_cvt_pk_bf16_f32 %0, %1, %2" : "=v"(r0) : "v"(p0), "v"(p1));
          asm("v_cvt_pk_bf16_f32 %0, %1, %2" : "=v"(r1) : "v"(p2), "v"(p3));
          uint2 rr; rr.x = r0; rr.y = r1;
          *(uint2*)((char*)Pl[wid] + cl * 144 + fc * 32 + hi * 8) = rr;
          ls += (p0 + p1) + (p2 + p3);
        }
        lrun += ls;
      };
      if (t == NTw - 1) smax(true); else smax(false);
      // ---- PV: A = P[q][key] (contiguous), B = V^T[d][key] ----
      __builtin_amdgcn_s_setprio(1);
#pragma unroll
      for (int kf = 0; kf < 2; ++kf) {
        short8 pa = *(const short8*)((const char*)Pl[wid] + cl * 144 + kf * 64 + hi * 16);
        const char* vbp = (const char*)Vl[cur] + (kf ? kvo1 : kvo0);
        short8 vb[4];
#pragma unroll
        for (int fc = 0; fc < 4; ++fc)
          vb[fc] = *(const short8*)(vbp + fc * 2048);
#pragma unroll
        for (int fc = 0; fc < 4; ++fc)
          o[fc] = MFMA16(pa, vb[fc], o[fc]);
      }
      __builtin_amdgcn_s_setprio(0);
    }
  }
  // ---- epilogue ----
  float l = lrun;
  l += __shfl_xor(l, 16);
  l += __shfl_xor(l, 32);   // lanes {cl,+16,+32,+48} hold full chunk-sum for query wq0+cl
  if (qt < 4) {
    // single chunk: normalize and write ao directly
    const int b = bh >> 4, h = bh & 15;
#pragma unroll
    for (int j = 0; j < 4; ++j) {
      float inv = 1.f / __shfl(l, hi * 4 + j);   // full sum for row hi*4+j
      int q = wq0 + hi * 4 + j;
#pragma unroll
      for (int fc = 0; fc < 4; ++fc) {
        size_t idx2 = ((size_t)b * 2048 + q) * 1024 + h * 64 + fc * 16 + cl;
        ao[idx2] = f2bf(o[fc][j] * inv);
      }
    }
  } else {
    // partial: unnormalized bf16 O + f32 l  (slot indexed by qt-4)
    const int slot = (bh * 12 + (qt - 4)) * 4 + c;
    u16* po = pO + (size_t)slot * 8192 + (size_t)wid * 16 * 64;
    if (hi == 0) pL[slot * 128 + wid * 16 + cl] = l;
#pragma unroll
    for (int j = 0; j < 4; ++j) {
      int row = hi * 4 + j;
#pragma unroll
      for (int fc = 0; fc < 4; ++fc)
        po[row * 64 + fc * 16 + cl] = f2bf(o[fc][j]);
    }
  }
}

// ---------------- attention partial reduce (vectorized x4) ----------------
// For qt>=4: ao[row] = (sum_c O_c[row]) / (sum_c l_c[row])
__global__ __launch_bounds__(256) void k_attn_reduce(const u16* __restrict__ pO,
                                                     const float* __restrict__ pL,
                                                     u16* __restrict__ ao) {
  int e = blockIdx.x * 256 + threadIdx.x;   // 32 bh x 12 qt x 128 row x 16 d4
  int d0 = (e & 15) * 4;
  int row = (e >> 4) & 127;
  int t = e >> 11;                          // bh*12 + (qt-4)
  int qt = 4 + t % 12;
  int bh = t / 12;
  int nch = (2 * qt + 9) >> 3;              // ceil((2qt+2)/8) in 2..4
  int slot = t * 4;
  size_t obase = (size_t)slot * 8192 + row * 64 + d0;
  float O0 = 0.f, O1 = 0.f, O2 = 0.f, O3 = 0.f, l = 0.f;
  for (int c = 0; c < nch; ++c) {
    u16x4 v = *(const u16x4*)(pO + obase + (size_t)c * 8192);
    O0 += bf2f(v.x); O1 += bf2f(v.y); O2 += bf2f(v.z); O3 += bf2f(v.w);
    l += pL[(slot + c) * 128 + row];
  }
  float inv = 1.f / l;
  u16x4 r = {f2bf(O0 * inv), f2bf(O1 * inv), f2bf(O2 * inv), f2bf(O3 * inv)};
  int b = bh >> 4, h = bh & 15;
  int q = qt * 128 + row;
  *(u16x4*)(ao + ((size_t)b * 2048 + q) * 1024 + h * 64 + d0) = r;
}

// ---------------- output projection (128x64 tile, 512 blocks = 2/CU) ----------------
__global__ __launch_bounds__(256) void k_out_gemm(const u16* __restrict__ ao,
                                                  const u16* __restrict__ woh,
                                                  const float* __restrict__ bo, float* __restrict__ out) {
  // XCD swizzle (T1): 512 blocks, 64/XCD -> each XCD owns 4 contiguous m-tiles x all 16 n
  int bid = blockIdx.x;
  int sid = (bid & 7) * 64 + (bid >> 3);
  int m0 = (sid >> 4) * 128, n0 = (sid & 15) * 64;
  floatx4 acc[4][2];
  gemm_main_n64(ao, woh, m0, n0, acc);
  const int lane = threadIdx.x & 63, wid = threadIdx.x >> 6;
  const int wr = wid >> 1, wc = wid & 1;
#pragma unroll
  for (int j = 0; j < 2; ++j) {
    int n = n0 + wc * 32 + j * 16 + (lane & 15);
    float bias = bo[n];
#pragma unroll
    for (int i = 0; i < 4; ++i) {
#pragma unroll
      for (int r = 0; r < 4; ++r) {
        int m = m0 + wr * 64 + i * 16 + (lane >> 4) * 4 + r;
        out[(size_t)m * 1024 + n] = acc[i][j][r] + bias;
      }
    }
  }
}

// ---------------- launch ----------------
extern "C" void kernel_launch(void* const* d_in, const int* in_sizes, int n_in,
                              void* d_out, int out_size, void* d_ws, size_t ws_size,
                              hipStream_t stream) {
  (void)in_sizes; (void)n_in; (void)out_size; (void)ws_size;
  const float* x    = (const float*)d_in[0];
  // d_in[1] = causal mask (tril) — implied by kernel structure, not read
  const float* Wqkv = (const float*)d_in[2];
  const float* bqkv = (const float*)d_in[3];
  const float* Wo   = (const float*)d_in[4];
  const float* bo   = (const float*)d_in[5];
  float* out = (float*)d_out;

  u16* p = (u16*)d_ws;
  u16* xh  = p; p += 4194304;   // [4096][1024] — reused as ao after QKV GEMM
  u16* wh  = p; p += 3145728;   // WqkvT [3072][1024] bf16
  u16* woh = p; p += 1048576;   // WoT   [1024][1024] bf16
  u16* Qb  = p; p += 4194304;   // [B*H][S][64]
  u16* Kb  = p; p += 4194304;
  u16* Vt  = p; p += 4194304;   // [B*H][64][S]
  u16* pO  = p; p += 12582912;  // partial O: [32*12*4 slots][128][64] bf16 (qt>=4)
  float* pL = (float*)p; p += 393216;  // partial l: [32*12*4][128] f32
  u16* ao  = xh;                // alias: x dead after QKV GEMM

  k_cast<<<4096, 256, 0, stream>>>(x, xh, 4194304);
  k_transpose<<<dim3(96, 32), dim3(32, 8), 0, stream>>>(Wqkv, wh, 1024, 3072);
  k_transpose<<<dim3(32, 32), dim3(32, 8), 0, stream>>>(Wo, woh, 1024, 1024);
  k_qkv_gemm<<<dim3(24, 32), 256, 0, stream>>>(xh, wh, bqkv, Qb, Kb, Vt);
  k_attn<<<1280, 512, 0, stream>>>(Qb, Kb, Vt, ao, pO, pL);
  k_attn_reduce<<<3072, 256, 0, stream>>>(pO, pL, ao);
  k_out_gemm<<<512, 256, 0, stream>>>(ao, woh, bo, out);
}

// Round 11
// 117.168 us; speedup vs baseline: 1.1720x; 1.0997x over previous
//
#include <hip/hip_runtime.h>
#include <hip/hip_bf16.h>

// Problem constants
#define S_LEN 2048
#define NHEAD 16
#define HDIM  64
#define DMODEL 1024

typedef unsigned short u16;
typedef __attribute__((ext_vector_type(8))) short short8;   // 8 x bf16 (4 VGPRs)
typedef __attribute__((ext_vector_type(4))) float floatx4;
typedef __attribute__((ext_vector_type(4))) u16 u16x4;

__device__ __forceinline__ u16 f2bf(float f) {
  unsigned u = __builtin_bit_cast(unsigned, f);
  u += 0x7fffu + ((u >> 16) & 1u);
  return (u16)(u >> 16);
}
__device__ __forceinline__ float bf2f(u16 b) {
  unsigned u = ((unsigned)b) << 16;
  return __builtin_bit_cast(float, u);
}
__device__ __forceinline__ void gload_lds16(const void* g, void* l) {
  __builtin_amdgcn_global_load_lds((const __attribute__((address_space(1))) unsigned int*)g,
                                   (__attribute__((address_space(3))) unsigned int*)l,
                                   16, 0, 0);
}
// XOR swizzle: spread row bits into the 16B-slot bits (involution, 16B granularity).
// Verified R2-R10: SQ_LDS_BANK_CONFLICT == 0 on staged K/V & GEMM tiles; read-side masks
// are lane-constant (row bits 7-9 depend only on lane) -> hoisted bases, immediate offsets.
__device__ __forceinline__ int swz(int b) { return b ^ (((b >> 7) & 7) << 4); }

#define MFMA16(a, b, c) __builtin_amdgcn_mfma_f32_16x16x32_bf16(a, b, c, 0, 0, 0)

// ---------------- fused prep: cast x + transpose Wqkv + transpose Wo ----------------
__global__ __launch_bounds__(256) void k_prep(const float* __restrict__ x,
                                              const float* __restrict__ Wqkv,
                                              const float* __restrict__ Wo,
                                              u16* __restrict__ xh,
                                              u16* __restrict__ wh,
                                              u16* __restrict__ woh) {
  int bid = blockIdx.x, tid = threadIdx.x;
  if (bid < 4096) {
    int i = (bid * 256 + tid) * 4;
    float4 v = *(const float4*)(x + i);
    u16x4 hv = {f2bf(v.x), f2bf(v.y), f2bf(v.z), f2bf(v.w)};
    *(u16x4*)(xh + i) = hv;
    return;
  }
  __shared__ float t[32][33];
  const float* in; u16* oh; int C, bx, by;
  if (bid < 7168) { int b = bid - 4096; in = Wqkv; oh = wh;  C = 3072; bx = b % 96; by = b / 96; }
  else            { int b = bid - 7168; in = Wo;   oh = woh; C = 1024; bx = b & 31; by = b >> 5; }
  const int R = 1024;
  int c0 = bx * 32, r0 = by * 32;
  int tx = tid & 31, ty = tid >> 5;
#pragma unroll
  for (int rr = ty; rr < 32; rr += 8) t[rr][tx] = in[(size_t)(r0 + rr) * C + c0 + tx];
  __syncthreads();
#pragma unroll
  for (int rr = ty; rr < 32; rr += 8)
    oh[(size_t)(c0 + rr) * R + r0 + tx] = f2bf(t[tx][rr]);
}

// ---------------- bf16 GEMM mainloop (m97 2-buffer structure, pool-based LDS) ----------------
// C[128x128] = A[128x1024] * B^T, B stored [N][K=1024].  sA/sB each [2][128*32] u16.
__device__ __forceinline__ void gemm_main(const u16* __restrict__ A, const u16* __restrict__ B,
                                          int m0, int n0, floatx4 (&acc)[4][4],
                                          u16* sA, u16* sB) {
  const int tid = threadIdx.x, lane = tid & 63;
  const int wid = tid >> 6, wr = wid >> 1, wc = wid & 1;
  const int cl = lane & 15, hi = lane >> 4;
  // hoisted swizzled read bases: b = w*4096 + i*1024 + cl*64 + hi*16, (b>>7)&7 == (cl>>1)&7
  const int rmask = ((cl >> 1) & 7) << 4;
  const int aoff = (wr * 4096 + cl * 64 + hi * 16) ^ rmask;
  const int boff = (wc * 4096 + cl * 64 + hi * 16) ^ rmask;
#pragma unroll
  for (int i = 0; i < 4; ++i)
#pragma unroll
    for (int j = 0; j < 4; ++j) acc[i][j] = (floatx4){0.f, 0.f, 0.f, 0.f};

  auto stage = [&](int buf, int kt) {   // 4 loads/thread
    int k0 = kt * 32;
#pragma unroll
    for (int it = 0; it < 2; ++it) {
      // linear LDS dest; source address pre-swizzled so swizzled reads see consistent data
      int p = (it * 256 + tid) * 16;
      int q = swz(p);
      int row = q >> 6, colb = q & 63;
      int base = buf * 8192 + (it * 256 + (tid & ~63)) * 16;   // wave-uniform LDS base
      gload_lds16((const char*)A + (size_t)(m0 + row) * 2048 + k0 * 2 + colb, (char*)sA + base);
      gload_lds16((const char*)B + (size_t)(n0 + row) * 2048 + k0 * 2 + colb, (char*)sB + base);
    }
  };
  stage(0, 0);
  __syncthreads();
  for (int kt = 0; kt < 32; ++kt) {
    int cur = kt & 1;
    if (kt + 1 < 32) stage(cur ^ 1, kt + 1);
    short8 a[4], b[4];
#pragma unroll
    for (int i = 0; i < 4; ++i) {
      a[i] = *(const short8*)((const char*)sA + cur * 8192 + aoff + i * 1024);
      b[i] = *(const short8*)((const char*)sB + cur * 8192 + boff + i * 1024);
    }
    __builtin_amdgcn_s_setprio(1);
#pragma unroll
    for (int i = 0; i < 4; ++i)
#pragma unroll
      for (int j = 0; j < 4; ++j)
        acc[i][j] = MFMA16(a[i], b[j], acc[i][j]);
    __builtin_amdgcn_s_setprio(0);
    __syncthreads();
  }
}

// ---------------- bf16 GEMM mainloop, 128x64 tile (for N=1024 out-proj: 512 blocks = 2/CU) ----------------
__device__ __forceinline__ void gemm_main_n64(const u16* __restrict__ A, const u16* __restrict__ B,
                                              int m0, int n0, floatx4 (&acc)[4][2]) {
  __shared__ __align__(16) u16 sA[2][128 * 32];
  __shared__ __align__(16) u16 sB[2][64 * 32];
  const int tid = threadIdx.x, lane = tid & 63;
  const int wid = tid >> 6, wr = wid >> 1, wc = wid & 1;
  const int cl = lane & 15, hi = lane >> 4;
  const int rmask = ((cl >> 1) & 7) << 4;
  const int aoff = (wr * 4096 + cl * 64 + hi * 16) ^ rmask;
  const int boff = (wc * 2048 + cl * 64 + hi * 16) ^ rmask;   // wave n-half = wc*32 rows
#pragma unroll
  for (int i = 0; i < 4; ++i)
#pragma unroll
    for (int j = 0; j < 2; ++j) acc[i][j] = (floatx4){0.f, 0.f, 0.f, 0.f};

  auto stage = [&](int buf, int kt) {   // 3 loads/thread (A: 2, B: 1)
    int k0 = kt * 32;
#pragma unroll
    for (int it = 0; it < 2; ++it) {
      int p = (it * 256 + tid) * 16;
      int q = swz(p);
      int row = q >> 6, colb = q & 63;
      int base = (it * 256 + (tid & ~63)) * 16;
      gload_lds16((const char*)A + (size_t)(m0 + row) * 2048 + k0 * 2 + colb, (char*)sA[buf] + base);
    }
    {
      int p = tid * 16;                 // 4KB B tile, one pass
      int q = swz(p);
      int row = q >> 6, colb = q & 63;
      int base = (tid & ~63) * 16;
      gload_lds16((const char*)B + (size_t)(n0 + row) * 2048 + k0 * 2 + colb, (char*)sB[buf] + base);
    }
  };
  stage(0, 0);
  __syncthreads();
  for (int kt = 0; kt < 32; ++kt) {
    int cur = kt & 1;
    if (kt + 1 < 32) stage(cur ^ 1, kt + 1);
    short8 a[4], b[2];
#pragma unroll
    for (int i = 0; i < 4; ++i)
      a[i] = *(const short8*)((const char*)sA[cur] + aoff + i * 1024);
#pragma unroll
    for (int j = 0; j < 2; ++j)
      b[j] = *(const short8*)((const char*)sB[cur] + boff + j * 1024);
    __builtin_amdgcn_s_setprio(1);
#pragma unroll
    for (int i = 0; i < 4; ++i)
#pragma unroll
      for (int j = 0; j < 2; ++j)
        acc[i][j] = MFMA16(a[i], b[j], acc[i][j]);
    __builtin_amdgcn_s_setprio(0);
    __syncthreads();
  }
}

// ---------------- QKV projection ----------------
// Writes Q,K as [B*H][S][64] bf16, V transposed as [B*H][64][S] bf16.
// R10 post-mortem: scalar-u16 epilogue scatter cost ~14us (derived from R3/R9 timing system).
// Fix: per-wave LDS bounce (reusing mainloop LDS) -> 8x 16B coalesced stores per thread.
// Key invariant: each wave's 64-n range is 64-aligned, and segment boundaries (rr=0/64/128)
// and h boundaries (192=3*64) are 64-aligned -> segment & h are WAVE-UNIFORM.
__global__ __launch_bounds__(256) void k_qkv_gemm(const u16* __restrict__ xh,
                                                  const u16* __restrict__ wh,
                                                  const float* __restrict__ bqkv,
                                                  u16* __restrict__ Qb, u16* __restrict__ Kb,
                                                  u16* __restrict__ Vt) {
  // XCD swizzle (T1): 768 blocks, 96/XCD (verified R8: FETCH 71.8 -> 28.8 MB)
  int bid = blockIdx.y * 24 + blockIdx.x;
  int sid = (bid & 7) * 96 + (bid >> 3);
  int m0 = (sid / 24) * 128, n0 = (sid % 24) * 128;
  // LDS pool: mainloop uses [0, 16384) u16 (sA 2x8KB, sB 2x8KB); epilogue bounce uses
  // 4 waves x 64 x 72 u16 = 18432 u16 (36KB). Union via shared pool.
  __shared__ __align__(16) u16 pool[18432];
  floatx4 acc[4][4];
  gemm_main(xh, wh, m0, n0, acc, pool, pool + 8192);
  // ---- epilogue: LDS bounce, coalesced 16B stores ----
  const int tid = threadIdx.x, lane = tid & 63, wid = tid >> 6;
  const int wr = wid >> 1, wc = wid & 1;
  const int cl = lane & 15, hi = lane >> 4;
  const int nbase = n0 + wc * 64;
  const int h = nbase / 192;          // wave-uniform
  const int rr0 = nbase - h * 192;    // 0 (Q), 64 (K), or 128 (V), wave-uniform
  const int mb = m0 + wr * 64;
  const int b = mb >> 11, s0 = mb & 2047;   // wave-uniform (64-range never crosses 2048)
  const int bh = b * 16 + h;
  u16* buf = pool + wid * 4608;       // per-wave [64][72]
  float bias[4];
#pragma unroll
  for (int j = 0; j < 4; ++j) bias[j] = bqkv[nbase + j * 16 + cl];
  // last gemm_main iteration ends with __syncthreads -> pool free for reuse
  if (rr0 < 128) {
    // Q/K wave: buf row-major [m_local][n_local]
#pragma unroll
    for (int j = 0; j < 4; ++j)
#pragma unroll
      for (int i = 0; i < 4; ++i)
#pragma unroll
        for (int r = 0; r < 4; ++r)
          buf[(i * 16 + hi * 4 + r) * 72 + j * 16 + cl] = f2bf(acc[i][j][r] + bias[j]);
    asm volatile("s_waitcnt lgkmcnt(0)" ::: "memory");
    u16* dst0 = (rr0 ? Kb : Qb) + ((size_t)bh * 2048 + s0) * 64;
#pragma unroll
    for (int k = 0; k < 8; ++k) {
      int m_l = k * 8 + (lane >> 3);
      short8 v = *(const short8*)&buf[m_l * 72 + (lane & 7) * 8];
      *(short8*)(dst0 + (size_t)m_l * 64 + (lane & 7) * 8) = v;   // 1KB contiguous per inst
    }
  } else {
    // V wave: buf transposed [n_local][m_local]
#pragma unroll
    for (int j = 0; j < 4; ++j)
#pragma unroll
      for (int i = 0; i < 4; ++i)
#pragma unroll
        for (int r = 0; r < 4; ++r)
          buf[(j * 16 + cl) * 72 + i * 16 + hi * 4 + r] = f2bf(acc[i][j][r] + bias[j]);
    asm volatile("s_waitcnt lgkmcnt(0)" ::: "memory");
    u16* dst0 = Vt + (size_t)bh * 64 * 2048 + s0;
#pragma unroll
    for (int k = 0; k < 8; ++k) {
      int nl = k * 8 + (lane >> 3);
      short8 v = *(const short8*)&buf[nl * 72 + (lane & 7) * 8];
      *(short8*)(dst0 + (size_t)nl * 2048 + (lane & 7) * 8) = v;  // 8x128B runs per inst
    }
  }
}

// ---------------- causal flash attention, KV-split ----------------
// Fixed-max softmax (p = exp(s/8 - 16), no rescale) makes attention LINEAR over key
// chunks: partial (O, l) from disjoint key ranges just add. Each block = (bh, qt, chunk
// of <=8 kv-tiles). qt<4 (single chunk): write ao directly. Else: write unnormalized
// bf16 partial O + f32 partial l; k_attn_reduce sums and normalizes.
// 8 waves x 16 q-rows, swapped QK^T, hoisted swizzle bases.
__global__ __launch_bounds__(512, 6) void k_attn(const u16* __restrict__ Qb,
                                                 const u16* __restrict__ Kb,
                                                 const u16* __restrict__ Vt,
                                                 u16* __restrict__ ao,
                                                 u16* __restrict__ pO,
                                                 float* __restrict__ pL) {
  // bid ordering: all 40 chunks of a bh land on XCD bh%8 (round-robin dispatch)
  const int bid = blockIdx.x;
  const int bh = (bid & 7) + 8 * ((bid >> 3) / 40);
  const int idx = (bid >> 3) % 40;
  int qt, c;
  if (idx < 4)        { qt = idx;                   c = 0; }
  else if (idx < 12)  { qt = 4 + ((idx - 4) >> 1);  c = (idx - 4) & 1; }
  else if (idx < 24)  { qt = 8 + (idx - 12) / 3;    c = (idx - 12) % 3; }
  else                { qt = 12 + ((idx - 24) >> 2); c = (idx - 24) & 3; }
  const int q0 = qt * 128;
  const int tid = threadIdx.x, lane = tid & 63, wid = tid >> 6;   // wid 0..7
  const int cl = lane & 15, hi = lane >> 4;
  const int wq0 = q0 + wid * 16;
  const int myq = wq0 + cl;
  const u16* Qp = Qb + (size_t)bh * (S_LEN * HDIM);
  const u16* Kp = Kb + (size_t)bh * (S_LEN * HDIM);
  const u16* Vp = Vt + (size_t)bh * (HDIM * S_LEN);

  __shared__ __align__(16) u16 Kl[2][64 * 64];
  __shared__ __align__(16) u16 Vl[2][64 * 64];
  __shared__ __align__(16) u16 Pl[8][16 * 72];   // per-wave 16 q-rows x 64 keys, 144B stride

  // hoisted swizzled K/V read bases: b = fc*2048 + cl*128 + kf*64 + hi*16, (b>>7)&7 == cl&7
  const int kvo0 = (cl * 128 + hi * 16) ^ ((cl & 7) << 4);
  const int kvo1 = kvo0 ^ 64;

  short8 qf[2];
#pragma unroll
  for (int kf = 0; kf < 2; ++kf)
    qf[kf] = *(const short8*)&Qp[(size_t)myq * 64 + kf * 32 + hi * 8];

  floatx4 o[4];
#pragma unroll
  for (int fc = 0; fc < 4; ++fc) o[fc] = (floatx4){0.f, 0.f, 0.f, 0.f};
  float lrun = 0.f;

  const int t0 = c * 8;
  const int NTb = min(t0 + 8, 2 * qt + 2);   // block tiles in this chunk
  const int NTw = 2 * qt + 1 + (wid >> 2);   // wave causal bound; t==NTw-1 is diagonal
  const float C1 = 0.125f * 1.44269504f;     // scale * log2(e)
  const float C2 = 16.0f * 1.44269504f;      // fixed max * log2(e)

  auto stage = [&](int buf, int kv0) {       // 2 loads/thread (512 threads)
    int p = tid * 16;
    int q = swz(p);
    int row = q >> 7, colb = q & 127;
    int base = (tid & ~63) * 16;
    gload_lds16((const char*)Kp + (size_t)(kv0 + row) * 128 + colb, (char*)Kl[buf] + base);
    gload_lds16((const char*)Vp + (size_t)row * 4096 + (size_t)kv0 * 2 + colb, (char*)Vl[buf] + base);
  };
  stage(0, t0 * 64);

  for (int t = t0; t < NTb; ++t) {
    int cur = t & 1;
    asm volatile("s_waitcnt vmcnt(0)" ::: "memory");
    __builtin_amdgcn_s_barrier();      // stage(t) landed; buf[t-1] readers done
    if (t + 1 < NTb) stage(cur ^ 1, (t + 1) * 64);
    if (t < NTw) {
      int kv0 = t * 64;
      // ---- QK^T (swapped: A=K, B=Q -> lane: query cl, keys fc*16+hi*4+j) ----
      floatx4 sc[4];
#pragma unroll
      for (int fc = 0; fc < 4; ++fc) sc[fc] = (floatx4){0.f, 0.f, 0.f, 0.f};
      __builtin_amdgcn_s_setprio(1);
#pragma unroll
      for (int kf = 0; kf < 2; ++kf) {
        const char* kb = (const char*)Kl[cur] + (kf ? kvo1 : kvo0);
        short8 kfv[4];
#pragma unroll
        for (int fc = 0; fc < 4; ++fc)
          kfv[fc] = *(const short8*)(kb + fc * 2048);
#pragma unroll
        for (int fc = 0; fc < 4; ++fc)
          sc[fc] = MFMA16(kfv[fc], qf[kf], sc[fc]);
      }
      __builtin_amdgcn_s_setprio(0);
      // ---- fixed-max softmax; mask only on the wave's diagonal (last) tile ----
      auto smax = [&](bool masked) {
        float ls = 0.f;
#pragma unroll
        for (int fc = 0; fc < 4; ++fc) {
          float p0 = exp2f(sc[fc][0] * C1 - C2);
          float p1 = exp2f(sc[fc][1] * C1 - C2);
          float p2 = exp2f(sc[fc][2] * C1 - C2);
          float p3 = exp2f(sc[fc][3] * C1 - C2);
          if (masked) {
            int key = kv0 + fc * 16 + hi * 4;
            p0 = (key + 0 <= myq) ? p0 : 0.f;
            p1 = (key + 1 <= myq) ? p1 : 0.f;
            p2 = (key + 2 <= myq) ? p2 : 0.f;
            p3 = (key + 3 <= myq) ? p3 : 0.f;
          }
          unsigned r0, r1;
          asm("v_cvt_pk_bf16_f32 %0, %1, %2" : "=v"(r0) : "v"(p0), "v"(p1));
          asm("v_cvt_pk_bf16_f32 %0, %1, %2" : "=v"(r1) : "v"(p2), "v"(p3));
          uint2 rr; rr.x = r0; rr.y = r1;
          *(uint2*)((char*)Pl[wid] + cl * 144 + fc * 32 + hi * 8) = rr;
          ls += (p0 + p1) + (p2 + p3);
        }
        lrun += ls;
      };
      if (t == NTw - 1) smax(true); else smax(false);
      // ---- PV: A = P[q][key] (contiguous), B = V^T[d][key] ----
      __builtin_amdgcn_s_setprio(1);
#pragma unroll
      for (int kf = 0; kf < 2; ++kf) {
        short8 pa = *(const short8*)((const char*)Pl[wid] + cl * 144 + kf * 64 + hi * 16);
        const char* vbp = (const char*)Vl[cur] + (kf ? kvo1 : kvo0);
        short8 vb[4];
#pragma unroll
        for (int fc = 0; fc < 4; ++fc)
          vb[fc] = *(const short8*)(vbp + fc * 2048);
#pragma unroll
        for (int fc = 0; fc < 4; ++fc)
          o[fc] = MFMA16(pa, vb[fc], o[fc]);
      }
      __builtin_amdgcn_s_setprio(0);
    }
  }
  // ---- epilogue ----
  float l = lrun;
  l += __shfl_xor(l, 16);
  l += __shfl_xor(l, 32);   // lanes {cl,+16,+32,+48} hold full chunk-sum for query wq0+cl
  if (qt < 4) {
    // single chunk: normalize and write ao directly
    const int b = bh >> 4, h = bh & 15;
#pragma unroll
    for (int j = 0; j < 4; ++j) {
      float inv = 1.f / __shfl(l, hi * 4 + j);   // full sum for row hi*4+j
      int q = wq0 + hi * 4 + j;
#pragma unroll
      for (int fc = 0; fc < 4; ++fc) {
        size_t idx2 = ((size_t)b * 2048 + q) * 1024 + h * 64 + fc * 16 + cl;
        ao[idx2] = f2bf(o[fc][j] * inv);
      }
    }
  } else {
    // partial: unnormalized bf16 O + f32 l  (slot indexed by qt-4)
    const int slot = (bh * 12 + (qt - 4)) * 4 + c;
    u16* po = pO + (size_t)slot * 8192 + (size_t)wid * 16 * 64;
    if (hi == 0) pL[slot * 128 + wid * 16 + cl] = l;
#pragma unroll
    for (int j = 0; j < 4; ++j) {
      int row = hi * 4 + j;
#pragma unroll
      for (int fc = 0; fc < 4; ++fc)
        po[row * 64 + fc * 16 + cl] = f2bf(o[fc][j]);
    }
  }
}

// ---------------- attention partial reduce (vectorized x4) ----------------
// For qt>=4: ao[row] = (sum_c O_c[row]) / (sum_c l_c[row])
__global__ __launch_bounds__(256) void k_attn_reduce(const u16* __restrict__ pO,
                                                     const float* __restrict__ pL,
                                                     u16* __restrict__ ao) {
  int e = blockIdx.x * 256 + threadIdx.x;   // 32 bh x 12 qt x 128 row x 16 d4
  int d0 = (e & 15) * 4;
  int row = (e >> 4) & 127;
  int t = e >> 11;                          // bh*12 + (qt-4)
  int qt = 4 + t % 12;
  int bh = t / 12;
  int nch = (2 * qt + 9) >> 3;              // ceil((2qt+2)/8) in 2..4
  int slot = t * 4;
  size_t obase = (size_t)slot * 8192 + row * 64 + d0;
  float O0 = 0.f, O1 = 0.f, O2 = 0.f, O3 = 0.f, l = 0.f;
  for (int c = 0; c < nch; ++c) {
    u16x4 v = *(const u16x4*)(pO + obase + (size_t)c * 8192);
    O0 += bf2f(v.x); O1 += bf2f(v.y); O2 += bf2f(v.z); O3 += bf2f(v.w);
    l += pL[(slot + c) * 128 + row];
  }
  float inv = 1.f / l;
  u16x4 r = {f2bf(O0 * inv), f2bf(O1 * inv), f2bf(O2 * inv), f2bf(O3 * inv)};
  int b = bh >> 4, h = bh & 15;
  int q = qt * 128 + row;
  *(u16x4*)(ao + ((size_t)b * 2048 + q) * 1024 + h * 64 + d0) = r;
}

// ---------------- output projection (128x64 tile, 512 blocks = 2/CU) ----------------
__global__ __launch_bounds__(256) void k_out_gemm(const u16* __restrict__ ao,
                                                  const u16* __restrict__ woh,
                                                  const float* __restrict__ bo, float* __restrict__ out) {
  // XCD swizzle (T1): 512 blocks, 64/XCD -> each XCD owns 4 contiguous m-tiles x all 16 n
  int bid = blockIdx.x;
  int sid = (bid & 7) * 64 + (bid >> 3);
  int m0 = (sid >> 4) * 128, n0 = (sid & 15) * 64;
  floatx4 acc[4][2];
  gemm_main_n64(ao, woh, m0, n0, acc);
  const int lane = threadIdx.x & 63, wid = threadIdx.x >> 6;
  const int wr = wid >> 1, wc = wid & 1;
#pragma unroll
  for (int j = 0; j < 2; ++j) {
    int n = n0 + wc * 32 + j * 16 + (lane & 15);
    float bias = bo[n];
#pragma unroll
    for (int i = 0; i < 4; ++i) {
#pragma unroll
      for (int r = 0; r < 4; ++r) {
        int m = m0 + wr * 64 + i * 16 + (lane >> 4) * 4 + r;
        out[(size_t)m * 1024 + n] = acc[i][j][r] + bias;
      }
    }
  }
}

// ---------------- launch ----------------
extern "C" void kernel_launch(void* const* d_in, const int* in_sizes, int n_in,
                              void* d_out, int out_size, void* d_ws, size_t ws_size,
                              hipStream_t stream) {
  (void)in_sizes; (void)n_in; (void)out_size; (void)ws_size;
  const float* x    = (const float*)d_in[0];
  // d_in[1] = causal mask (tril) — implied by kernel structure, not read
  const float* Wqkv = (const float*)d_in[2];
  const float* bqkv = (const float*)d_in[3];
  const float* Wo   = (const float*)d_in[4];
  const float* bo   = (const float*)d_in[5];
  float* out = (float*)d_out;

  u16* p = (u16*)d_ws;
  u16* xh  = p; p += 4194304;   // [4096][1024] — reused as ao after QKV GEMM
  u16* wh  = p; p += 3145728;   // WqkvT [3072][1024] bf16
  u16* woh = p; p += 1048576;   // WoT   [1024][1024] bf16
  u16* Qb  = p; p += 4194304;   // [B*H][S][64]
  u16* Kb  = p; p += 4194304;
  u16* Vt  = p; p += 4194304;   // [B*H][64][S]
  u16* pO  = p; p += 12582912;  // partial O: [32*12*4 slots][128][64] bf16 (qt>=4)
  float* pL = (float*)p; p += 393216;  // partial l: [32*12*4][128] f32
  u16* ao  = xh;                // alias: x dead after QKV GEMM

  k_prep<<<8192, 256, 0, stream>>>(x, Wqkv, Wo, xh, wh, woh);
  k_qkv_gemm<<<dim3(24, 32), 256, 0, stream>>>(xh, wh, bqkv, Qb, Kb, Vt);
  k_attn<<<1280, 512, 0, stream>>>(Qb, Kb, Vt, ao, pO, pL);
  k_attn_reduce<<<3072, 256, 0, stream>>>(pO, pL, ao);
  k_out_gemm<<<512, 256, 0, stream>>>(ao, woh, bo, out);
}